// Round 2
// baseline (241.620 us; speedup 1.0000x reference)
//
#include <hip/hip_runtime.h>

// KLD RepPoints loss, R7: fused single-kernel + non-temporal reads.
// History: R0/R1 60us floor = same-line atomics (WRITE_SIZE betrayed it).
// R2 two-kernel ~32us kernel = best. R3 (block LDS staging), R4 (float4
// gather) regressed. R5 (4 elem/thread, 52 outstanding loads) = NULL ->
// not latency-bound. R6 (per-wave coalesced global_load_lds staging,
// double-buffered, counted vmcnt) = NULL -> not L1-transaction-bound
// either. Conclusion: partial-kernel time is PATTERN-INDEPENDENT at
// ~3.4 TB/s read; the two 302-MB harness poison fills (2x45.5us) dominate
// the 135us total and are untouchable.
// R7 attacks the only two remaining levers:
//   (a) dispatch count: last-block-done fused reduction kills the final
//       kernel + its launch gap (counter zeroed via 4B hipMemsetAsync);
//   (b) cache policy: inputs are touched exactly once and L3 was just
//       flushed by the fill -> __builtin_nontemporal_load (nt bit) skips
//       L3 allocate on the read stream. Cheapest proven-equal pattern
//       otherwise: direct float2/float4 gather, 2 elem/thread, 2048 blocks.

typedef float v2f __attribute__((ext_vector_type(2)));
typedef float v4f __attribute__((ext_vector_type(4)));

#define EPT 2   // elements per thread

__device__ __forceinline__ float kld_elem(
    const float px[9], const float py[9],
    const float tx[4], const float ty[4])
{
    // ---- pred moments ----
    const float inv9 = 1.0f / 9.0f;
    float sx = 0.f, sy = 0.f;
    #pragma unroll
    for (int k = 0; k < 9; ++k) { sx += px[k]; sy += py[k]; }
    float mux = sx * inv9, muy = sy * inv9;
    float a = 0.f, b = 0.f, d = 0.f;   // p_var = [[a,b],[b,d]]
    #pragma unroll
    for (int k = 0; k < 9; ++k) {
        float xx = px[k] - mux, yy = py[k] - muy;
        a += xx * xx; b += xx * yy; d += yy * yy;
    }
    a = a * inv9 + 1e-6f;
    b = b * inv9;
    d = d * inv9 + 1e-6f;

    // ---- target box -> rotated Gaussian ----
    float tmux = (tx[0] + tx[1] + tx[2] + tx[3]) * 0.25f;
    float tmuy = (ty[0] + ty[1] + ty[2] + ty[3]) * 0.25f;
    float e1x = tx[1] - tx[0], e1y = ty[1] - ty[0];
    float e2x = tx[2] - tx[1], e2y = ty[2] - ty[1];
    float w = e1x * e1x + e1y * e1y;
    float h = e2x * e2x + e2y * e2y;
    float sw = sqrtf(w);
    float c = e1x / sw, s = e1y / sw;
    const float invLL = 1.0f / 36.0f;      // 1/(4*L*L), L=3
    float dw = w * invLL, dh = h * invLL;
    float tv00 = c * c * dw + s * s * dh;  // t_var = R diag(dw,dh) R^T
    float tv01 = c * s * (dw - dh);
    float tv11 = s * s * dw + c * c * dh;

    float t_det = tv00 * tv11 - tv01 * tv01;
    float p_det = a * d - b * b;
    float inv_tdet = 1.0f / t_det;

    float dx = mux - tmux, dy = muy - tmuy;
    float term1 = (dx * dx * tv11 - 2.0f * dx * dy * tv01 + dy * dy * tv00) * inv_tdet;
    float trace = (tv11 * a - 2.0f * tv01 * b + tv00 * d) * inv_tdet;
    float term2 = trace + logf(t_det / p_det);
    float kld = 0.5f * (term1 + term2) - 1.0f;
    float kl = fmaxf(kld, 1e-6f);
    return 1.0f - 1.0f / (2.0f + sqrtf(kl));
}

__global__ __launch_bounds__(256) void kld_fused_kernel(
    const float* __restrict__ pred,    // [n][9][2]
    const float* __restrict__ target,  // [n][4][2]
    float* __restrict__ out,           // [1]
    float* __restrict__ ws,            // [0]=counter(uint), [1..nblocks]=partials
    int n_total, float inv_n)
{
    const int tid    = threadIdx.x;
    const int idx0   = blockIdx.x * 256 + tid;
    const int stride = gridDim.x * 256;

    float loss = 0.0f;

    #pragma unroll
    for (int i = 0; i < EPT; ++i) {
        int e = idx0 + i * stride;
        if (e < n_total) {
            const v2f* p = reinterpret_cast<const v2f*>(pred) + (size_t)e * 9;
            const v4f* t = reinterpret_cast<const v4f*>(target) + (size_t)e * 2;
            // streaming (nt) loads: touched-once data, L3 just flushed by
            // the harness fill -> skip L3 allocate on the read path
            v2f p0 = __builtin_nontemporal_load(p + 0);
            v2f p1 = __builtin_nontemporal_load(p + 1);
            v2f p2 = __builtin_nontemporal_load(p + 2);
            v2f p3 = __builtin_nontemporal_load(p + 3);
            v2f p4 = __builtin_nontemporal_load(p + 4);
            v2f p5 = __builtin_nontemporal_load(p + 5);
            v2f p6 = __builtin_nontemporal_load(p + 6);
            v2f p7 = __builtin_nontemporal_load(p + 7);
            v2f p8 = __builtin_nontemporal_load(p + 8);
            v4f t01 = __builtin_nontemporal_load(t + 0);  // 32B/elem, 16B aligned
            v4f t23 = __builtin_nontemporal_load(t + 1);

            float px[9] = {p0.x, p1.x, p2.x, p3.x, p4.x, p5.x, p6.x, p7.x, p8.x};
            float py[9] = {p0.y, p1.y, p2.y, p3.y, p4.y, p5.y, p6.y, p7.y, p8.y};
            float tx[4] = {t01.x, t01.z, t23.x, t23.z};
            float ty[4] = {t01.y, t01.w, t23.y, t23.w};
            loss += kld_elem(px, py, tx, ty);
        }
    }

    // ---- block reduction: wave64 shuffle -> LDS ----
    #pragma unroll
    for (int off = 32; off > 0; off >>= 1)
        loss += __shfl_down(loss, off, 64);

    __shared__ float sm[4];
    __shared__ int amLast;
    const int lane = tid & 63;
    const int wid  = tid >> 6;
    if (lane == 0) sm[wid] = loss;
    __syncthreads();

    // ---- last-block-done fused finalization ----
    if (tid == 0) {
        float bsum = sm[0] + sm[1] + sm[2] + sm[3];
        ws[1 + blockIdx.x] = bsum;
        __threadfence();   // release: partial visible device-wide before count
        unsigned prev = atomicAdd(reinterpret_cast<unsigned*>(ws), 1u);
        amLast = (prev == gridDim.x - 1);
    }
    __syncthreads();

    if (amLast) {                    // block-uniform branch
        __threadfence();             // acquire: see all other blocks' partials
        float s = 0.0f;
        const int nb = (int)gridDim.x;
        for (int i = tid; i < nb; i += 256)
            s += ws[1 + i];

        #pragma unroll
        for (int off = 32; off > 0; off >>= 1)
            s += __shfl_down(s, off, 64);

        if (lane == 0) sm[wid] = s;  // sm reuse safe: writes after 2nd sync
        __syncthreads();
        if (tid == 0)
            out[0] = (sm[0] + sm[1] + sm[2] + sm[3]) * inv_n;
    }
}

extern "C" void kernel_launch(void* const* d_in, const int* in_sizes, int n_in,
                              void* d_out, int out_size, void* d_ws, size_t ws_size,
                              hipStream_t stream) {
    const float* pred   = (const float*)d_in[0];
    const float* target = (const float*)d_in[1];
    float* out = (float*)d_out;
    float* ws  = (float*)d_ws;

    int n = in_sizes[0] / 18;   // N elements (pred is N*9*2 floats)
    int nblocks = (n + 256 * EPT - 1) / (256 * EPT);
    if (nblocks < 1) nblocks = 1;

    // zero the arrival counter (ws[0]); graph-capture-safe stream op
    hipMemsetAsync(d_ws, 0, 4, stream);

    kld_fused_kernel<<<nblocks, 256, 0, stream>>>(
        pred, target, out, ws, n, 1.0f / (float)n);
}

// Round 3
// 183.978 us; speedup vs baseline: 1.3133x; 1.3133x over previous
//
#include <hip/hip_runtime.h>

// KLD RepPoints loss, R8: fused single-kernel, PLAIN cached loads.
// History: R0/R1 60us floor = same-line atomics. R2 two-kernel ~32us
// kernel = best baseline (135us total incl. 91us harness poison fills).
// R3 (block LDS staging), R4 (float4 pred-pair gather) regressed.
// R5 (4 elem/thread) NULL -> not latency-bound. R6 (coalesced
// global_load_lds staging, counted vmcnt) NULL -> not L1-transaction
// bound. R7 (nt loads + fused tail) = DISASTER, and diagnostic gold:
// fused kernel ran 137us FLAT whether FETCH was 64MB or 131KB ->
// nt (no-allocate) defeats L2 line-sharing on the stride-72 gather;
// every 8B request pulled its own 64B line from L3 (~700MB L3 traffic
// = the 137us). NEVER use nt on gathers where lanes share lines.
// R8: keep R7's fusion (last-block-done reduction, kills the final
// kernel + gap; 4B memset zeroes the arrival counter since the harness
// poisons the workspace), revert loads to the proven R5 pattern:
// plain float2 pred gather, float4 target (16B-aligned), EPT=4,
// 1024 blocks. Expected fused kernel ~35-40us, total ~128us.

typedef float v2f __attribute__((ext_vector_type(2)));
typedef float v4f __attribute__((ext_vector_type(4)));

#define EPT 4   // elements per thread

__device__ __forceinline__ float kld_elem(
    const float px[9], const float py[9],
    const float tx[4], const float ty[4])
{
    // ---- pred moments ----
    const float inv9 = 1.0f / 9.0f;
    float sx = 0.f, sy = 0.f;
    #pragma unroll
    for (int k = 0; k < 9; ++k) { sx += px[k]; sy += py[k]; }
    float mux = sx * inv9, muy = sy * inv9;
    float a = 0.f, b = 0.f, d = 0.f;   // p_var = [[a,b],[b,d]]
    #pragma unroll
    for (int k = 0; k < 9; ++k) {
        float xx = px[k] - mux, yy = py[k] - muy;
        a += xx * xx; b += xx * yy; d += yy * yy;
    }
    a = a * inv9 + 1e-6f;
    b = b * inv9;
    d = d * inv9 + 1e-6f;

    // ---- target box -> rotated Gaussian ----
    float tmux = (tx[0] + tx[1] + tx[2] + tx[3]) * 0.25f;
    float tmuy = (ty[0] + ty[1] + ty[2] + ty[3]) * 0.25f;
    float e1x = tx[1] - tx[0], e1y = ty[1] - ty[0];
    float e2x = tx[2] - tx[1], e2y = ty[2] - ty[1];
    float w = e1x * e1x + e1y * e1y;
    float h = e2x * e2x + e2y * e2y;
    float sw = sqrtf(w);
    float c = e1x / sw, s = e1y / sw;
    const float invLL = 1.0f / 36.0f;      // 1/(4*L*L), L=3
    float dw = w * invLL, dh = h * invLL;
    float tv00 = c * c * dw + s * s * dh;  // t_var = R diag(dw,dh) R^T
    float tv01 = c * s * (dw - dh);
    float tv11 = s * s * dw + c * c * dh;

    float t_det = tv00 * tv11 - tv01 * tv01;
    float p_det = a * d - b * b;
    float inv_tdet = 1.0f / t_det;

    float dx = mux - tmux, dy = muy - tmuy;
    float term1 = (dx * dx * tv11 - 2.0f * dx * dy * tv01 + dy * dy * tv00) * inv_tdet;
    float trace = (tv11 * a - 2.0f * tv01 * b + tv00 * d) * inv_tdet;
    float term2 = trace + logf(t_det / p_det);
    float kld = 0.5f * (term1 + term2) - 1.0f;
    float kl = fmaxf(kld, 1e-6f);
    return 1.0f - 1.0f / (2.0f + sqrtf(kl));
}

__global__ __launch_bounds__(256) void kld_fused_kernel(
    const float* __restrict__ pred,    // [n][9][2]
    const float* __restrict__ target,  // [n][4][2]
    float* __restrict__ out,           // [1]
    float* __restrict__ ws,            // [0]=counter(uint), [1..nblocks]=partials
    int n_total, float inv_n)
{
    const int tid    = threadIdx.x;
    const int idx0   = blockIdx.x * 256 + tid;
    const int stride = gridDim.x * 256;

    float loss = 0.0f;

    #pragma unroll
    for (int i = 0; i < EPT; ++i) {
        int e = idx0 + i * stride;
        if (e < n_total) {
            const v2f* p = reinterpret_cast<const v2f*>(pred) + (size_t)e * 9;
            const v4f* t = reinterpret_cast<const v4f*>(target) + (size_t)e * 2;
            v2f p0 = p[0], p1 = p[1], p2 = p[2], p3 = p[3], p4 = p[4],
                p5 = p[5], p6 = p[6], p7 = p[7], p8 = p[8];
            v4f t01 = t[0], t23 = t[1];

            float px[9] = {p0.x, p1.x, p2.x, p3.x, p4.x, p5.x, p6.x, p7.x, p8.x};
            float py[9] = {p0.y, p1.y, p2.y, p3.y, p4.y, p5.y, p6.y, p7.y, p8.y};
            float tx[4] = {t01.x, t01.z, t23.x, t23.z};
            float ty[4] = {t01.y, t01.w, t23.y, t23.w};
            loss += kld_elem(px, py, tx, ty);
        }
    }

    // ---- block reduction: wave64 shuffle -> LDS ----
    #pragma unroll
    for (int off = 32; off > 0; off >>= 1)
        loss += __shfl_down(loss, off, 64);

    __shared__ float sm[4];
    __shared__ int amLast;
    const int lane = tid & 63;
    const int wid  = tid >> 6;
    if (lane == 0) sm[wid] = loss;
    __syncthreads();

    // ---- last-block-done fused finalization ----
    if (tid == 0) {
        float bsum = sm[0] + sm[1] + sm[2] + sm[3];
        ws[1 + blockIdx.x] = bsum;
        __threadfence();   // release: partial visible device-wide before count
        unsigned prev = atomicAdd(reinterpret_cast<unsigned*>(ws), 1u);
        amLast = (prev == gridDim.x - 1);
    }
    __syncthreads();

    if (amLast) {                    // block-uniform branch
        __threadfence();             // acquire: see all other blocks' partials
        float s = 0.0f;
        const int nb = (int)gridDim.x;
        for (int i = tid; i < nb; i += 256)
            s += ws[1 + i];

        #pragma unroll
        for (int off = 32; off > 0; off >>= 1)
            s += __shfl_down(s, off, 64);

        if (lane == 0) sm[wid] = s;  // sm reuse safe: writes after 2nd sync
        __syncthreads();
        if (tid == 0)
            out[0] = (sm[0] + sm[1] + sm[2] + sm[3]) * inv_n;
    }
}

extern "C" void kernel_launch(void* const* d_in, const int* in_sizes, int n_in,
                              void* d_out, int out_size, void* d_ws, size_t ws_size,
                              hipStream_t stream) {
    const float* pred   = (const float*)d_in[0];
    const float* target = (const float*)d_in[1];
    float* out = (float*)d_out;
    float* ws  = (float*)d_ws;

    int n = in_sizes[0] / 18;   // N elements (pred is N*9*2 floats)
    int nblocks = (n + 256 * EPT - 1) / (256 * EPT);
    if (nblocks < 1) nblocks = 1;

    // zero the arrival counter (ws[0]); graph-capture-safe stream op.
    // Needed every launch: the harness poisons the whole workspace.
    hipMemsetAsync(d_ws, 0, 4, stream);

    kld_fused_kernel<<<nblocks, 256, 0, stream>>>(
        pred, target, out, ws, n, 1.0f / (float)n);
}

// Round 6
// 134.396 us; speedup vs baseline: 1.7978x; 1.3689x over previous
//
#include <hip/hip_runtime.h>

// KLD RepPoints loss, R11: third submission of the proven-best two-kernel
// structure (R5/R9/R10 identical). R9 and R10 both hit broker-side
// "container failed twice" errors with NO GPU-side evidence; this exact
// code benched cleanly at ~135us in earlier rounds. Do not mutate
// working code on infrastructure errors.
//
// Full history / falsification ledger:
//   R0/R1: 60us floor = 4096 same-line atomicAdds (~15ns each; WRITE_SIZE
//          betrayed it). R2 two-kernel no-atomics = best, ~32us partial.
//   R3 block-wide LDS staging: REGRESSED.
//   R4 float4 pred-pair gather: REGRESSED.
//   R5 EPT=4 gather (this code): NULL vs R2 -> not latency/MLP-bound.
//   R6 per-wave coalesced global_load_lds + counted vmcnt: NULL ->
//          not L1-transaction-bound.
//   R7 nontemporal loads: +100us. nt defeats L2 line-sharing on stride-72
//          gather (~700MB L3 traffic, runtime flat vs FETCH). NEVER nt a
//          gather where lanes share cache lines.
//   R8 last-block-done fusion (threadfence + same-line counter atomics):
//          fused kernel 85us vs 36us for partial+final. Per-block release
//          fence + 1024 same-line atomics ~= +50us; also dropped VGPR to
//          24 (compiler serialized loads). FALSIFIED.
// Structural floor accounting (cross-checked vs R6/R8 totals):
//   91us  2x 288MiB harness poison fills @83% HBM peak  (untouchable)
//   32us  partial kernel: 109MB (~55 HBM + ~55 L3) at ~3.4 TB/s effective;
//         IDENTICAL across 5 structurally different load schemes ->
//         pattern-independent read floor for this dispatch
//    4us  final 1-block reduction
//   ~8us  launch gaps + harness restore dispatches
// => ~135us total. This file is that best-known configuration.

__device__ __forceinline__ float kld_elem(
    const float px[9], const float py[9],
    const float tx[4], const float ty[4])
{
    // ---- pred moments ----
    const float inv9 = 1.0f / 9.0f;
    float sx = 0.f, sy = 0.f;
    #pragma unroll
    for (int k = 0; k < 9; ++k) { sx += px[k]; sy += py[k]; }
    float mux = sx * inv9, muy = sy * inv9;
    float a = 0.f, b = 0.f, d = 0.f;   // p_var = [[a,b],[b,d]]
    #pragma unroll
    for (int k = 0; k < 9; ++k) {
        float xx = px[k] - mux, yy = py[k] - muy;
        a += xx * xx; b += xx * yy; d += yy * yy;
    }
    a = a * inv9 + 1e-6f;
    b = b * inv9;
    d = d * inv9 + 1e-6f;

    // ---- target box -> rotated Gaussian ----
    float tmux = (tx[0] + tx[1] + tx[2] + tx[3]) * 0.25f;
    float tmuy = (ty[0] + ty[1] + ty[2] + ty[3]) * 0.25f;
    float e1x = tx[1] - tx[0], e1y = ty[1] - ty[0];
    float e2x = tx[2] - tx[1], e2y = ty[2] - ty[1];
    float w = e1x * e1x + e1y * e1y;
    float h = e2x * e2x + e2y * e2y;
    float sw = sqrtf(w);
    float c = e1x / sw, s = e1y / sw;
    const float invLL = 1.0f / 36.0f;      // 1/(4*L*L), L=3
    float dw = w * invLL, dh = h * invLL;
    float tv00 = c * c * dw + s * s * dh;  // t_var = R diag(dw,dh) R^T
    float tv01 = c * s * (dw - dh);
    float tv11 = s * s * dw + c * c * dh;

    float t_det = tv00 * tv11 - tv01 * tv01;
    float p_det = a * d - b * b;
    float inv_tdet = 1.0f / t_det;

    float dx = mux - tmux, dy = muy - tmuy;
    float term1 = (dx * dx * tv11 - 2.0f * dx * dy * tv01 + dy * dy * tv00) * inv_tdet;
    float trace = (tv11 * a - 2.0f * tv01 * b + tv00 * d) * inv_tdet;
    float term2 = trace + logf(t_det / p_det);
    float kld = 0.5f * (term1 + term2) - 1.0f;
    float kl = fmaxf(kld, 1e-6f);
    return 1.0f - 1.0f / (2.0f + sqrtf(kl));
}

#define ELEMS_PER_THREAD 4

__global__ __launch_bounds__(256) void kld_partial_kernel(
    const float* __restrict__ pred,    // [n][9][2]
    const float* __restrict__ target,  // [n][4][2]
    float* __restrict__ ws,            // [gridDim.x] partial sums
    int n_total)
{
    const int idx0   = blockIdx.x * 256 + threadIdx.x;
    const int stride = gridDim.x * 256;

    float loss = 0.0f;

    #pragma unroll
    for (int i = 0; i < ELEMS_PER_THREAD; ++i) {
        int e = idx0 + i * stride;
        if (e < n_total) {
            const float2* p = reinterpret_cast<const float2*>(pred) + (size_t)e * 9;
            const float2* t = reinterpret_cast<const float2*>(target) + (size_t)e * 4;
            float2 p0 = p[0], p1 = p[1], p2 = p[2], p3 = p[3], p4 = p[4],
                   p5 = p[5], p6 = p[6], p7 = p[7], p8 = p[8];
            float2 q0 = t[0], q1 = t[1], q2 = t[2], q3 = t[3];

            float px[9] = {p0.x, p1.x, p2.x, p3.x, p4.x, p5.x, p6.x, p7.x, p8.x};
            float py[9] = {p0.y, p1.y, p2.y, p3.y, p4.y, p5.y, p6.y, p7.y, p8.y};
            float tx[4] = {q0.x, q1.x, q2.x, q3.x};
            float ty[4] = {q0.y, q1.y, q2.y, q3.y};
            loss += kld_elem(px, py, tx, ty);
        }
    }

    // ---- reduction: wave64 shuffle -> LDS -> one plain store per block ----
    #pragma unroll
    for (int off = 32; off > 0; off >>= 1)
        loss += __shfl_down(loss, off, 64);

    __shared__ float sm[4];
    int lane = threadIdx.x & 63;
    int wid  = threadIdx.x >> 6;
    if (lane == 0) sm[wid] = loss;
    __syncthreads();
    if (threadIdx.x == 0)
        ws[blockIdx.x] = sm[0] + sm[1] + sm[2] + sm[3];
}

__global__ __launch_bounds__(256) void kld_final_kernel(
    const float* __restrict__ ws, float* __restrict__ out,
    int nblocks, float inv_n)
{
    float s = 0.0f;
    for (int i = threadIdx.x; i < nblocks; i += 256)
        s += ws[i];

    #pragma unroll
    for (int off = 32; off > 0; off >>= 1)
        s += __shfl_down(s, off, 64);

    __shared__ float sm[4];
    int lane = threadIdx.x & 63;
    int wid  = threadIdx.x >> 6;
    if (lane == 0) sm[wid] = s;
    __syncthreads();
    if (threadIdx.x == 0)
        out[0] = (sm[0] + sm[1] + sm[2] + sm[3]) * inv_n;
}

extern "C" void kernel_launch(void* const* d_in, const int* in_sizes, int n_in,
                              void* d_out, int out_size, void* d_ws, size_t ws_size,
                              hipStream_t stream) {
    const float* pred   = (const float*)d_in[0];
    const float* target = (const float*)d_in[1];
    float* out = (float*)d_out;
    float* ws  = (float*)d_ws;

    int n = in_sizes[0] / 18;   // N elements (pred is N*9*2 floats)
    int nblocks = (n + 256 * ELEMS_PER_THREAD - 1) / (256 * ELEMS_PER_THREAD);
    if (nblocks < 1) nblocks = 1;

    kld_partial_kernel<<<nblocks, 256, 0, stream>>>(pred, target, ws, n);
    kld_final_kernel<<<1, 256, 0, stream>>>(ws, out, nblocks, 1.0f / (float)n);
}